// Round 2
// baseline (164.721 us; speedup 1.0000x reference)
//
#include <hip/hip_runtime.h>

typedef unsigned short u16;
typedef unsigned int   u32;
typedef unsigned long long u64;
typedef short bf16x8 __attribute__((ext_vector_type(8)));
typedef float f32x4  __attribute__((ext_vector_type(4)));
typedef float f32x2  __attribute__((ext_vector_type(2)));

#define MFMA(a,b,c) __builtin_amdgcn_mfma_f32_16x16x32_bf16((a),(b),(c),0,0,0)

__device__ __forceinline__ float bf2f(u16 a) {
  u32 u = ((u32)a) << 16;
  return __builtin_bit_cast(float, u);
}
__device__ __forceinline__ u16 f2bf(float f) {
  u32 u = __builtin_bit_cast(u32, f);
  u32 r = u + 0x7FFFu + ((u >> 16) & 1u);
  return (u16)(r >> 16);
}

// ---------------- LDS layout (bytes) ----------------
// Q:   [64 q][64 c] bf16, XOR-swizzled rows        (8192)
// K:   [144 pix][64 c] bf16, XOR-swizzled rows     (18432)
// V:   [64 c][168 pix] bf16 linear (pix 144..167 zeroed) (21504)
// U:   union { x-patch [144][64] swz (18432) } then { 8 wave P-strips 32x40 bf16 (20480) }
// ATT: [64 q][64 c] bf16 swz                       (8192)
// LSUM: 8 waves * 32 f32 reciprocal row-sums       (1024)
constexpr int Q_OFF    = 0;
constexpr int K_OFF    = 8192;
constexpr int V_OFF    = 26624;
constexpr int U_OFF    = 48128;
constexpr int ATT_OFF  = U_OFF + 20480;   // 68608
constexpr int LSUM_OFF = U_OFF + 28672;   // 76800
constexpr int SMEM_BYTES = LSUM_OFF + 1024; // 77824

// Expand rpb_table into MFMA D-fragment order (f32), premultiplied by log2(e).
// layout: frag = (h*4+tq)*9+tk ; per frag 64 lanes * 4 f32 (r=0..3)
__global__ __launch_bounds__(256)
void bias_expand(const float* __restrict__ rpb, float* __restrict__ bexp)
{
  int gid = blockIdx.x * 256 + threadIdx.x;      // < 9216
  int frag = gid >> 6, l = gid & 63;
  int hh = frag / 36, rem = frag % 36, tq = rem / 9, tk = rem % 9;
  int lg = (l >> 4) & 3;
  int kp = tk * 16 + (l & 15);
  int ky = kp / 12, kx = kp % 12;
  f32x4 v;
#pragma unroll
  for (int r = 0; r < 4; ++r) {
    int q = tq * 16 + lg * 4 + r;
    int idx = (ky - (q >> 3) + 7) * 19 + (kx - (q & 7) + 7);
    v[r] = rpb[idx * 4 + hh] * 1.4426950408889634f;
  }
  *(f32x4*)(bexp + (size_t)gid * 4) = v;
}

__global__ __launch_bounds__(512)
void fused_win_attn(const float* __restrict__ x, const float* __restrict__ qkv_w,
                    const float* __restrict__ qkv_b, const float* __restrict__ proj_w,
                    const float* __restrict__ proj_b, const float* __restrict__ bexp,
                    float* __restrict__ out)
{
  __shared__ __align__(16) char smem[SMEM_BYTES];
  char* Sm = smem;
  const int tid = threadIdx.x;
  const int l   = tid & 63;
  const int wv  = tid >> 6;        // wave 0..7
  const int l15 = l & 15;
  const int lg  = l >> 4;          // 0..3

  // XCD-aware swizzle (4096 % 8 == 0, bijective)
  int bid = blockIdx.x;
  int win = (bid & 7) * 512 + (bid >> 3);
  const int bb = win >> 10;
  const int wl = win & 1023;
  const int wy = wl >> 5, wx = wl & 31;
  const int oy = wy * 8, ox = wx * 8;
  const int py0 = oy - 2, px0 = ox - 2;

  // ---- Phase 0: zero V pad cols 144..167, stage x patch (bf16, swz [pix][c]) ----
  if (tid < 384) {
    int row = tid / 6, j = tid % 6;
    *(u64*)(Sm + V_OFF + row * 336 + 288 + j * 8) = 0ull;
  }
  {
    const float* xb = x + (size_t)bb * 64 * 65536;
#pragma unroll
    for (int it = 0; it < 9; ++it) {
      int u = it * 512 + tid;            // < 4608 = 64c * 72 pixel-pairs
      int c = u / 72, pp = u % 72;
      int prow = pp / 6, pc2 = (pp % 6) * 2;
      int gy = py0 + prow, gx = px0 + pc2;   // gx always even -> pair never straddles edge
      f32x2 val = {0.f, 0.f};
      if ((u32)gy < 256u && (u32)gx < 256u)
        val = *(const f32x2*)(xb + (size_t)c * 65536 + gy * 256 + gx);
      int pix0 = prow * 12 + pc2;
      *(u16*)(Sm + U_OFF + ((pix0 * 128 + c * 2) ^ ((pix0 & 7) << 4))) = f2bf(val[0]);
      int pix1 = pix0 + 1;
      *(u16*)(Sm + U_OFF + ((pix1 * 128 + c * 2) ^ ((pix1 & 7) << 4))) = f2bf(val[1]);
    }
  }
  __syncthreads();

  // ---- Phase 1: QKV pointwise GEMM -> q/k/v LDS ----
  {
    int mt = 4 + wv;   // kv M-tiles: out channels 64..191
    const float* wr = qkv_w + (size_t)(mt * 16 + l15) * 64;
    f32x4 w0 = *(const f32x4*)(wr + lg * 8);
    f32x4 w1 = *(const f32x4*)(wr + lg * 8 + 4);
    f32x4 w2 = *(const f32x4*)(wr + 32 + lg * 8);
    f32x4 w3 = *(const f32x4*)(wr + 32 + lg * 8 + 4);
    bf16x8 a0, a1;
#pragma unroll
    for (int j = 0; j < 4; ++j) {
      a0[j] = f2bf(w0[j]); a0[4 + j] = f2bf(w1[j]);
      a1[j] = f2bf(w2[j]); a1[4 + j] = f2bf(w3[j]);
    }
    float qb[4];
#pragma unroll
    for (int r = 0; r < 4; ++r) qb[r] = qkv_b[mt * 16 + lg * 4 + r];
#pragma unroll
    for (int nt = 0; nt < 9; ++nt) {
      int pix = nt * 16 + l15;
      int swz = (pix & 7) << 4;
      bf16x8 b0 = *(const bf16x8*)(Sm + U_OFF + ((pix * 128 + lg * 16) ^ swz));
      bf16x8 b1 = *(const bf16x8*)(Sm + U_OFF + ((pix * 128 + 64 + lg * 16) ^ swz));
      f32x4 acc = {0.f, 0.f, 0.f, 0.f};
      acc = MFMA(a0, b0, acc);
      acc = MFMA(a1, b1, acc);
      if (mt < 8) {          // k channels
        u64 pk = 0;
#pragma unroll
        for (int r = 0; r < 4; ++r) pk |= (u64)f2bf(acc[r] + qb[r]) << (16 * r);
        int ocl = (mt - 4) * 16 + lg * 4;
        *(u64*)(Sm + K_OFF + ((pix * 128 + ocl * 2) ^ swz)) = pk;
      } else {               // v channels
        int ocv = (mt - 8) * 16 + lg * 4;
#pragma unroll
        for (int r = 0; r < 4; ++r)
          *(u16*)(Sm + V_OFF + (ocv + r) * 336 + pix * 2) = f2bf(acc[r] + qb[r]);
      }
    }
    if (wv < 4) {            // q M-tiles: out channels 0..63, inner 8x8 pixels only
      int mtq = wv;
      const float* wq = qkv_w + (size_t)(mtq * 16 + l15) * 64;
      f32x4 u0 = *(const f32x4*)(wq + lg * 8);
      f32x4 u1 = *(const f32x4*)(wq + lg * 8 + 4);
      f32x4 u2 = *(const f32x4*)(wq + 32 + lg * 8);
      f32x4 u3 = *(const f32x4*)(wq + 32 + lg * 8 + 4);
      bf16x8 c0, c1;
#pragma unroll
      for (int j = 0; j < 4; ++j) {
        c0[j] = f2bf(u0[j]); c0[4 + j] = f2bf(u1[j]);
        c1[j] = f2bf(u2[j]); c1[4 + j] = f2bf(u3[j]);
      }
      float qb2[4];
#pragma unroll
      for (int r = 0; r < 4; ++r) qb2[r] = qkv_b[mtq * 16 + lg * 4 + r];
#pragma unroll
      for (int nt = 0; nt < 4; ++nt) {
        int q = nt * 16 + l15;
        int pix = ((q >> 3) + 2) * 12 + (q & 7) + 2;
        int swz = (pix & 7) << 4;
        bf16x8 b0 = *(const bf16x8*)(Sm + U_OFF + ((pix * 128 + lg * 16) ^ swz));
        bf16x8 b1 = *(const bf16x8*)(Sm + U_OFF + ((pix * 128 + 64 + lg * 16) ^ swz));
        f32x4 acc = {0.f, 0.f, 0.f, 0.f};
        acc = MFMA(c0, b0, acc);
        acc = MFMA(c1, b1, acc);
        u64 pk = 0;
#pragma unroll
        for (int r = 0; r < 4; ++r)   // fold SCALE * log2(e) into q
          pk |= (u64)f2bf((acc[r] + qb2[r]) * 0.36067376022224085f) << (16 * r);
        int ocl = mtq * 16 + lg * 4;
        *(u64*)(Sm + Q_OFF + ((q * 128 + ocl * 2) ^ ((q & 7) << 4))) = pk;
      }
    }
  }
  __syncthreads();

  // ---- Phase 2: per-wave (head, q-half) QK^T + bias + softmax ----
  const int h = wv >> 1, qh = wv & 1;
  bf16x8 zfrag = {0, 0, 0, 0, 0, 0, 0, 0};
  bf16x8 aq0 = zfrag, aq1 = zfrag;
  if (l < 32) {            // K=32 MFMA but reduction d=16: lanes 32..63 carry zeros
    int q0 = (qh * 2) * 16 + l15;
    aq0 = *(const bf16x8*)(Sm + Q_OFF + ((q0 * 128 + h * 32 + lg * 16) ^ ((q0 & 7) << 4)));
    int q1 = (qh * 2 + 1) * 16 + l15;
    aq1 = *(const bf16x8*)(Sm + Q_OFF + ((q1 * 128 + h * 32 + lg * 16) ^ ((q1 & 7) << 4)));
  }
  f32x4 sA[9], sB[9];
  {
    f32x4 zf = {0.f, 0.f, 0.f, 0.f};
#pragma unroll
    for (int tk = 0; tk < 9; ++tk) { sA[tk] = zf; sB[tk] = zf; }
  }
#pragma unroll
  for (int tk = 0; tk < 9; ++tk) {
    bf16x8 bk = zfrag;
    if (l < 32) {
      int kp = tk * 16 + l15;
      bk = *(const bf16x8*)(Sm + K_OFF + ((kp * 128 + h * 32 + lg * 16) ^ ((kp & 7) << 4)));
    }
    sA[tk] = MFMA(aq0, bk, sA[tk]);
    sB[tk] = MFMA(aq1, bk, sB[tk]);
  }
  {
#pragma unroll
    for (int tk = 0; tk < 9; ++tk) {
      f32x4 w0 = *(const f32x4*)(bexp + ((size_t)(((h * 4 + qh * 2 + 0) * 9) + tk) * 64 + l) * 4);
      f32x4 w1 = *(const f32x4*)(bexp + ((size_t)(((h * 4 + qh * 2 + 1) * 9) + tk) * 64 + l) * 4);
#pragma unroll
      for (int r = 0; r < 4; ++r) { sA[tk][r] += w0[r]; sB[tk][r] += w1[r]; }
    }
  }
  // softmax over 144 keys (rows live across 16-lane groups; log2 domain)
  float mA[4], mB[4], rA[4], rB[4];
#pragma unroll
  for (int r = 0; r < 4; ++r) {
    float ma = sA[0][r], mb = sB[0][r];
#pragma unroll
    for (int tk = 1; tk < 9; ++tk) { ma = fmaxf(ma, sA[tk][r]); mb = fmaxf(mb, sB[tk][r]); }
#pragma unroll
    for (int d = 1; d < 16; d <<= 1) {
      ma = fmaxf(ma, __shfl_xor(ma, d));
      mb = fmaxf(mb, __shfl_xor(mb, d));
    }
    mA[r] = ma; mB[r] = mb;
  }
#pragma unroll
  for (int r = 0; r < 4; ++r) {
    float sa = 0.f, sb = 0.f;
#pragma unroll
    for (int tk = 0; tk < 9; ++tk) {
      float pa = exp2f(sA[tk][r] - mA[r]);
      float pb = exp2f(sB[tk][r] - mB[r]);
      sA[tk][r] = pa; sB[tk][r] = pb;
      sa += pa; sb += pb;
    }
#pragma unroll
    for (int d = 1; d < 16; d <<= 1) {
      sa += __shfl_xor(sa, d);
      sb += __shfl_xor(sb, d);
    }
    rA[r] = sa; rB[r] = sb;
  }
  if (l15 == 0) {   // one lane per 16-group stores reciprocal row sums
    f32x4 ia, ib;
#pragma unroll
    for (int r = 0; r < 4; ++r) { ia[r] = 1.0f / rA[r]; ib[r] = 1.0f / rB[r]; }
    *(f32x4*)(Sm + LSUM_OFF + wv * 128 + lg * 16) = ia;
    *(f32x4*)(Sm + LSUM_OFF + wv * 128 + 64 + lg * 16) = ib;
  }

  // ---- Phase 3: PV via wave-private LDS P-strips (no barriers) ----
  f32x4 oA = {0.f, 0.f, 0.f, 0.f}, oB = {0.f, 0.f, 0.f, 0.f};
  const int pbase = U_OFF + wv * 2560;   // 32 rows x 40 bf16 (stride 80B)
#pragma unroll
  for (int s5 = 0; s5 < 5; ++s5) {
#pragma unroll
    for (int th = 0; th < 2; ++th) {
      int tk = 2 * s5 + th;
      int koff = (th * 16 + l15) * 2;
#pragma unroll
      for (int r = 0; r < 4; ++r) {
        u16 va = 0, vb = 0;
        if (tk < 9) { va = f2bf(sA[tk][r]); vb = f2bf(sB[tk][r]); }
        *(u16*)(Sm + pbase + (lg * 4 + r) * 80 + koff) = va;
        *(u16*)(Sm + pbase + (16 + lg * 4 + r) * 80 + koff) = vb;
      }
    }
    bf16x8 vf = *(const bf16x8*)(Sm + V_OFF + (h * 16 + l15) * 336 + s5 * 64 + lg * 16);
    bf16x8 pA = *(const bf16x8*)(Sm + pbase + l15 * 80 + lg * 16);
    bf16x8 pB = *(const bf16x8*)(Sm + pbase + (16 + l15) * 80 + lg * 16);
    oA = MFMA(vf, pA, oA);
    oB = MFMA(vf, pB, oB);
  }
  {
    float livA = *(const float*)(Sm + LSUM_OFF + wv * 128 + l15 * 4);
    float livB = *(const float*)(Sm + LSUM_OFF + wv * 128 + 64 + l15 * 4);
    int q0 = qh * 32 + l15;
    int c0 = h * 16 + lg * 4;
    u64 pk = 0;
#pragma unroll
    for (int r = 0; r < 4; ++r) pk |= (u64)f2bf(oA[r] * livA) << (16 * r);
    *(u64*)(Sm + ATT_OFF + ((q0 * 128 + c0 * 2) ^ ((q0 & 7) << 4))) = pk;
    int q1 = q0 + 16;
    u64 pk2 = 0;
#pragma unroll
    for (int r = 0; r < 4; ++r) pk2 |= (u64)f2bf(oB[r] * livB) << (16 * r);
    *(u64*)(Sm + ATT_OFF + ((q1 * 128 + c0 * 2) ^ ((q1 & 7) << 4))) = pk2;
  }
  __syncthreads();

  // ---- Phase 4: output projection + store (f32) ----
  {
    int mt = wv >> 1;
    const float* pr = proj_w + (size_t)(mt * 16 + l15) * 64;
    f32x4 w0 = *(const f32x4*)(pr + lg * 8);
    f32x4 w1 = *(const f32x4*)(pr + lg * 8 + 4);
    f32x4 w2 = *(const f32x4*)(pr + 32 + lg * 8);
    f32x4 w3 = *(const f32x4*)(pr + 32 + lg * 8 + 4);
    bf16x8 a0, a1;
#pragma unroll
    for (int j = 0; j < 4; ++j) {
      a0[j] = f2bf(w0[j]); a0[4 + j] = f2bf(w1[j]);
      a1[j] = f2bf(w2[j]); a1[4 + j] = f2bf(w3[j]);
    }
    float pbv[4];
#pragma unroll
    for (int r = 0; r < 4; ++r) pbv[r] = proj_b[mt * 16 + lg * 4 + r];
#pragma unroll
    for (int nn = 0; nn < 2; ++nn) {
      int nt = (wv & 1) * 2 + nn;
      int q = nt * 16 + l15;
      int swz = (q & 7) << 4;
      bf16x8 b0 = *(const bf16x8*)(Sm + ATT_OFF + ((q * 128 + lg * 16) ^ swz));
      bf16x8 b1 = *(const bf16x8*)(Sm + ATT_OFF + ((q * 128 + 64 + lg * 16) ^ swz));
      f32x4 acc = {0.f, 0.f, 0.f, 0.f};
      acc = MFMA(a0, b0, acc);
      acc = MFMA(a1, b1, acc);
      int gy = oy + (q >> 3), gx = ox + (q & 7);
      int o0 = mt * 16 + lg * 4;
      float* yp = out + (((size_t)bb * 64 + o0) * 256 + gy) * 256 + gx;
#pragma unroll
      for (int r = 0; r < 4; ++r) yp[(size_t)r * 65536] = acc[r] + pbv[r];
    }
  }
}

extern "C" void kernel_launch(void* const* d_in, const int* in_sizes, int n_in,
                              void* d_out, int out_size, void* d_ws, size_t ws_size,
                              hipStream_t stream) {
  const float* x      = (const float*)d_in[0];
  const float* qkv_w  = (const float*)d_in[1];
  const float* qkv_b  = (const float*)d_in[2];
  const float* rpb    = (const float*)d_in[3];
  const float* proj_w = (const float*)d_in[4];
  const float* proj_b = (const float*)d_in[5];
  float* out  = (float*)d_out;
  float* bexp = (float*)d_ws;   // 147456 bytes

  bias_expand<<<36, 256, 0, stream>>>(rpb, bexp);
  fused_win_attn<<<4096, 512, 0, stream>>>(x, qkv_w, qkv_b, proj_w, proj_b, bexp, out);
}

// Round 3
// 125.464 us; speedup vs baseline: 1.3129x; 1.3129x over previous
//
#include <hip/hip_runtime.h>

typedef unsigned short u16;
typedef unsigned int   u32;
typedef unsigned long long u64;
typedef short bf16x8 __attribute__((ext_vector_type(8)));
typedef float f32x4  __attribute__((ext_vector_type(4)));

#define MFMA(a,b,c) __builtin_amdgcn_mfma_f32_16x16x32_bf16((a),(b),(c),0,0,0)

#if __has_builtin(__builtin_amdgcn_exp2f)
#define EXP2F(x) __builtin_amdgcn_exp2f(x)
#else
#define EXP2F(x) exp2f(x)
#endif
#if __has_builtin(__builtin_amdgcn_rcpf)
#define RCPF(x) __builtin_amdgcn_rcpf(x)
#else
#define RCPF(x) (1.0f/(x))
#endif

// hardware packed f32->bf16 (RNE), 1 VALU op for 2 values [guide T12, m214v22]
__device__ __forceinline__ u32 cvt_pk(float lo, float hi) {
  u32 r;
  asm("v_cvt_pk_bf16_f32 %0, %1, %2" : "=v"(r) : "v"(lo), "v"(hi));
  return r;
}
union FragU { u32 u[4]; bf16x8 v; };
__device__ __forceinline__ bf16x8 frag2(u32 a, u32 b) {
  FragU x; x.u[0] = a; x.u[1] = b; x.u[2] = 0; x.u[3] = 0; return x.v;
}
__device__ __forceinline__ bf16x8 frag4(u32 a, u32 b, u32 c, u32 d) {
  FragU x; x.u[0] = a; x.u[1] = b; x.u[2] = c; x.u[3] = d; return x.v;
}
// 8 consecutive f32 -> bf16x8 fragment
__device__ __forceinline__ bf16x8 wfrag(const float* p) {
  f32x4 w0 = *(const f32x4*)p;
  f32x4 w1 = *(const f32x4*)(p + 4);
  return frag4(cvt_pk(w0[0], w0[1]), cvt_pk(w0[2], w0[3]),
               cvt_pk(w1[0], w1[1]), cvt_pk(w1[2], w1[3]));
}

// ---------------- LDS layout (bytes) ----------------
// K:  [144 pix][64 ch] bf16, XOR-swizzled rows                 18432
// V:  [64 ch][168 cols] bf16, cols = kpv-permuted key index    21504
// U:  xpatch [144 pix][64 ch] bf16 swz (phase 0-1)             18432
//     then ATT [64 q][64 ch] bf16 swz (phase 3-4)
constexpr int K_OFF = 0;
constexpr int V_OFF = 18432;
constexpr int U_OFF = 39936;
constexpr int SMEM_BYTES = 58368;

// SCALE * log2(e) = 0.25 * 1.4426950408889634
constexpr float SC_LOG2E = 0.36067376022224085f;

// Bias in S^T fragment order: frag f = (h*4 + qt)*9 + tk; lane l; f32x4 over r.
// value: lane (l15 = q-within-tile, lg), reg r -> q = qt*16+l15, p = tk*16+lg*4+r
__global__ __launch_bounds__(256)
void bias_expand(const float* __restrict__ rpb, float* __restrict__ bexp)
{
  int gid = blockIdx.x * 256 + threadIdx.x;      // < 9216
  int frag = gid >> 6, l = gid & 63;
  int hh = frag / 36, rem = frag % 36, qt = rem / 9, tk = rem % 9;
  int l15 = l & 15, lg = l >> 4;
  int q = qt * 16 + l15;
  int qy = q >> 3, qx = q & 7;
  f32x4 v;
#pragma unroll
  for (int r = 0; r < 4; ++r) {
    int p = tk * 16 + lg * 4 + r;
    int ky = p / 12, kx = p - ky * 12;
    int idx = (ky - qy + 7) * 19 + (kx - qx + 7);
    v[r] = rpb[idx * 4 + hh] * 1.4426950408889634f;
  }
  *(f32x4*)(bexp + (size_t)gid * 4) = v;
}

__global__ __launch_bounds__(512, 4)
void fused_win_attn(const float* __restrict__ x, const float* __restrict__ qkv_w,
                    const float* __restrict__ qkv_b, const float* __restrict__ proj_w,
                    const float* __restrict__ proj_b, const float* __restrict__ bexp,
                    float* __restrict__ out)
{
  __shared__ __align__(16) char Sm[SMEM_BYTES];
  const int tid = threadIdx.x;
  const int l   = tid & 63;
  const int wv  = tid >> 6;        // wave 0..7
  const int l15 = l & 15;
  const int lg  = l >> 4;          // 0..3
  const int h   = wv >> 1, qh = wv & 1;

  // XCD-aware bijective swizzle (4096 % 8 == 0)
  int bid = blockIdx.x;
  int win = (bid & 7) * 512 + (bid >> 3);
  const int bb = win >> 10;
  const int wl = win & 1023;
  const int oy = (wl >> 5) * 8, ox = (wl & 31) * 8;
  const int py0 = oy - 2, px0 = ox - 2;

  // ---- Phase 0: zero V cols 128..159 (kpv pad), stage x patch bf16 swz ----
  {
    int ch = tid >> 3, j = tid & 7;
    *(u64*)(Sm + V_OFF + ch * 336 + 256 + j * 8) = 0ull;
  }
  {
    const float* xb = x + (size_t)bb * 64 * 65536;
    int pix = tid % 144;         // pixel 0..143
    int cq  = tid / 144;         // channel-quad 0..15
#pragma unroll
    for (int it = 0; it < 5; ++it) {
      if (it < 4 || tid < 256) { // total 2304 units = 144 pix * 16 ch-quads
        int prow = (pix * 171) >> 11;      // pix / 12 for pix < 144
        int pcol = pix - prow * 12;
        int gy = py0 + prow, gx = px0 + pcol;
        float v0 = 0.f, v1 = 0.f, v2 = 0.f, v3 = 0.f;
        if (((u32)gy < 256u) & ((u32)gx < 256u)) {
          const float* p = xb + (size_t)(cq * 4) * 65536 + gy * 256 + gx;
          v0 = p[0]; v1 = p[65536]; v2 = p[131072]; v3 = p[196608];
        }
        u64 pk = (u64)cvt_pk(v0, v1) | ((u64)cvt_pk(v2, v3) << 32);
        *(u64*)(Sm + U_OFF + ((pix * 128 + cq * 8) ^ ((pix & 7) << 4))) = pk;
      }
      pix += 80; int wr = (pix >= 144); pix -= wr ? 144 : 0; cq += 3 + wr;
    }
  }
  __syncthreads();

  // ---- Phase 1: QKV GEMMs. K->LDS [pix][ch], V->LDS [ch][kpv], Q in-reg ----
  if (wv < 4) {
    // K channels tile wv (qkv rows 64+wv*16..): D[m=ch, n=pix]
    const float* wr_ = qkv_w + (size_t)(64 + wv * 16 + l15) * 64;
    bf16x8 a0 = wfrag(wr_ + lg * 8), a1 = wfrag(wr_ + 32 + lg * 8);
    float kb[4];
#pragma unroll
    for (int r = 0; r < 4; ++r) kb[r] = qkv_b[64 + wv * 16 + lg * 4 + r];
#pragma unroll
    for (int nt = 0; nt < 9; ++nt) {
      int pix = nt * 16 + l15;
      int swz = (pix & 7) << 4;
      bf16x8 b0 = *(const bf16x8*)(Sm + U_OFF + ((pix * 128 + lg * 16) ^ swz));
      bf16x8 b1 = *(const bf16x8*)(Sm + U_OFF + ((pix * 128 + 64 + lg * 16) ^ swz));
      f32x4 acc = {0.f, 0.f, 0.f, 0.f};
      acc = MFMA(a0, b0, acc);
      acc = MFMA(a1, b1, acc);
      u64 pk = (u64)cvt_pk(acc[0] + kb[0], acc[1] + kb[1]) |
               ((u64)cvt_pk(acc[2] + kb[2], acc[3] + kb[3]) << 32);
      *(u64*)(Sm + K_OFF + ((pix * 128 + wv * 32 + lg * 8) ^ swz)) = pk;
    }
  } else {
    // V channels tile vt (qkv rows 128+vt*16..): orientation-2 D[m=pix, n=ch]
    int vt = wv - 4;
    const float* wr_ = qkv_w + (size_t)(128 + vt * 16 + l15) * 64;
    bf16x8 bw0 = wfrag(wr_ + lg * 8), bw1 = wfrag(wr_ + 32 + lg * 8);
    float vb = qkv_b[128 + vt * 16 + l15];
#pragma unroll
    for (int nt = 0; nt < 9; ++nt) {
      int pr = nt * 16 + l15;
      int swz = (pr & 7) << 4;
      bf16x8 a0 = *(const bf16x8*)(Sm + U_OFF + ((pr * 128 + lg * 16) ^ swz));
      bf16x8 a1 = *(const bf16x8*)(Sm + U_OFF + ((pr * 128 + 64 + lg * 16) ^ swz));
      f32x4 acc = {0.f, 0.f, 0.f, 0.f};
      acc = MFMA(a0, bw0, acc);
      acc = MFMA(a1, bw1, acc);
      // rows m = pix = nt*16+lg*4+r -> kpv col = (nt>>1)*32 + lg*8 + (nt&1)*4 + r
      int colb = (nt >> 1) * 64 + lg * 16 + (nt & 1) * 8;   // *2 bytes
      u64 pk = (u64)cvt_pk(acc[0] + vb, acc[1] + vb) |
               ((u64)cvt_pk(acc[2] + vb, acc[3] + vb) << 32);
      *(u64*)(Sm + V_OFF + (vt * 16 + l15) * 336 + colb) = pk;
    }
  }
  // Q for this wave's own (h, qh): D[ch-tile h][q-tiles 2qh,2qh+1], kept in-reg
  u32 qf[2][2];
  {
    const float* wq = qkv_w + (size_t)(h * 16 + l15) * 64;
    bf16x8 qa0 = wfrag(wq + lg * 8), qa1 = wfrag(wq + 32 + lg * 8);
    float qsb[4];
#pragma unroll
    for (int r = 0; r < 4; ++r) qsb[r] = qkv_b[h * 16 + lg * 4 + r] * SC_LOG2E;
#pragma unroll
    for (int t = 0; t < 2; ++t) {
      int q = (qh * 2 + t) * 16 + l15;
      int pix = ((q >> 3) + 2) * 12 + (q & 7) + 2;
      int swz = (pix & 7) << 4;
      bf16x8 b0 = *(const bf16x8*)(Sm + U_OFF + ((pix * 128 + lg * 16) ^ swz));
      bf16x8 b1 = *(const bf16x8*)(Sm + U_OFF + ((pix * 128 + 64 + lg * 16) ^ swz));
      f32x4 acc = {0.f, 0.f, 0.f, 0.f};
      acc = MFMA(qa0, b0, acc);
      acc = MFMA(qa1, b1, acc);
      qf[t][0] = cvt_pk(acc[0] * SC_LOG2E + qsb[0], acc[1] * SC_LOG2E + qsb[1]);
      qf[t][1] = cvt_pk(acc[2] * SC_LOG2E + qsb[2], acc[3] * SC_LOG2E + qsb[3]);
    }
  }
  __syncthreads();

  // ---- Phase 2+3: per (head, q-16-tile): QK^T + bias + softmax + PV, no LDS P ----
  const int kcol = h * 32 + lg * 8;
#pragma unroll
  for (int half = 0; half < 2; ++half) {
    const bf16x8 bq = frag2(qf[half][0], qf[half][1]);
    f32x4 s[9];
#pragma unroll
    for (int tk = 0; tk < 9; ++tk) {
      int p = tk * 16 + l15;
      u64 kk = *(const u64*)(Sm + K_OFF + ((p * 128 + kcol) ^ ((p & 7) << 4)));
      f32x4 z = {0.f, 0.f, 0.f, 0.f};
      s[tk] = MFMA(frag2((u32)kk, (u32)(kk >> 32)), bq, z);
    }
    const int qt = qh * 2 + half;
    const float* bp_ = bexp + ((size_t)((h * 4 + qt) * 9) * 64 + l) * 4;
#pragma unroll
    for (int tk = 0; tk < 9; ++tk) {
      f32x4 bv = *(const f32x4*)(bp_ + tk * 256);
#pragma unroll
      for (int r = 0; r < 4; ++r) s[tk][r] += bv[r];
    }
    // softmax over 144 keys: 36 in-lane + lanes {l15, l15+16, +32, +48}
    float mx = s[0][0];
#pragma unroll
    for (int tk = 0; tk < 9; ++tk)
#pragma unroll
      for (int r = 0; r < 4; ++r) mx = fmaxf(mx, s[tk][r]);
    mx = fmaxf(mx, __shfl_xor(mx, 16));
    mx = fmaxf(mx, __shfl_xor(mx, 32));
    float sum = 0.f;
#pragma unroll
    for (int tk = 0; tk < 9; ++tk)
#pragma unroll
      for (int r = 0; r < 4; ++r) {
        float pv = EXP2F(s[tk][r] - mx);
        s[tk][r] = pv;
        sum += pv;
      }
    sum += __shfl_xor(sum, 16);
    sum += __shfl_xor(sum, 32);
    float rs = RCPF(sum);
    // pack P into PV B-fragments in-register (kpv permutation makes this exact)
    u32 pk[9][2];
#pragma unroll
    for (int tk = 0; tk < 9; ++tk) {
      pk[tk][0] = cvt_pk(s[tk][0], s[tk][1]);
      pk[tk][1] = cvt_pk(s[tk][2], s[tk][3]);
    }
    f32x4 o = {0.f, 0.f, 0.f, 0.f};
#pragma unroll
    for (int s5 = 0; s5 < 5; ++s5) {
      bf16x8 av = *(const bf16x8*)(Sm + V_OFF + (h * 16 + l15) * 336 + s5 * 64 + lg * 16);
      bf16x8 bp = (s5 < 4) ? frag4(pk[2*s5][0], pk[2*s5][1], pk[2*s5+1][0], pk[2*s5+1][1])
                           : frag2(pk[8][0], pk[8][1]);
      o = MFMA(av, bp, o);
    }
    // D: m = ch-within-head (lg*4+r), n = q = l15 -> ATT[q][h*16+lg*4..]
    int q = (qh * 2 + half) * 16 + l15;
    u64 pko = (u64)cvt_pk(o[0] * rs, o[1] * rs) |
              ((u64)cvt_pk(o[2] * rs, o[3] * rs) << 32);
    *(u64*)(Sm + U_OFF + ((q * 128 + kcol) ^ ((q & 7) << 4))) = pko;
  }
  __syncthreads();

  // ---- Phase 4: projection, orientation-2: D[m=q, n=och], f32x4 stores ----
  {
    int mt = wv & 3;
    int nb = (wv >> 2) * 2;
    int q = mt * 16 + l15, swz = (q & 7) << 4;
    bf16x8 aa0 = *(const bf16x8*)(Sm + U_OFF + ((q * 128 + lg * 16) ^ swz));
    bf16x8 aa1 = *(const bf16x8*)(Sm + U_OFF + ((q * 128 + 64 + lg * 16) ^ swz));
    int qrow = mt * 16 + lg * 4;
    int gy = oy + (qrow >> 3), gx = ox + (qrow & 7);
#pragma unroll
    for (int nn = 0; nn < 2; ++nn) {
      int ntile = nb + nn;
      const float* pw = proj_w + (size_t)(ntile * 16 + l15) * 64;
      bf16x8 b0 = wfrag(pw + lg * 8), b1 = wfrag(pw + 32 + lg * 8);
      f32x4 acc = {0.f, 0.f, 0.f, 0.f};
      acc = MFMA(aa0, b0, acc);
      acc = MFMA(aa1, b1, acc);
      float pb = proj_b[ntile * 16 + l15];
      f32x4 st = {acc[0] + pb, acc[1] + pb, acc[2] + pb, acc[3] + pb};
      float* yp = out + (((size_t)bb * 64 + ntile * 16 + l15) * 256 + gy) * 256 + gx;
      *(f32x4*)yp = st;
    }
  }
}

extern "C" void kernel_launch(void* const* d_in, const int* in_sizes, int n_in,
                              void* d_out, int out_size, void* d_ws, size_t ws_size,
                              hipStream_t stream) {
  const float* x      = (const float*)d_in[0];
  const float* qkv_w  = (const float*)d_in[1];
  const float* qkv_b  = (const float*)d_in[2];
  const float* rpb    = (const float*)d_in[3];
  const float* proj_w = (const float*)d_in[4];
  const float* proj_b = (const float*)d_in[5];
  float* out  = (float*)d_out;
  float* bexp = (float*)d_ws;   // 147456 bytes

  bias_expand<<<36, 256, 0, stream>>>(rpb, bexp);
  fused_win_attn<<<4096, 512, 0, stream>>>(x, qkv_w, qkv_b, proj_w, proj_b, bexp, out);
}